// Round 4
// baseline (1043.740 us; speedup 1.0000x reference)
//
#include <hip/hip_runtime.h>
#include <math.h>
#include <float.h>

// Problem constants (reference: B=8, T=2048, D=256, K=8192)
#define N_TOK 16384            // B*T
#define DIM   256
#define KCODES 8192
#define KSPLIT 4
#define KRANGE (KCODES / KSPLIT)   // 2048 codes per split
#define BT 64                  // token tile
#define BK 64                  // code tile
#define BD 64                  // d chunk
#define OUT_Q (N_TOK * DIM)    // 4194304 floats: quantized
#define OUT_I OUT_Q            // idx (as float) starts here, N_TOK elems
// loss scalar at OUT_Q + N_TOK

// ws layout (floats):
//   invu    [0, 16384)              per-token 1/ulp(||x||^2)
//   part_r  [16384, 16384+65536)    per-split best quantized score (float)
//   part_i  [81920, 81920+65536)    per-split best index (int)
//   lpart   [147456, +1024)

// ---------------- Kernel A: per-token 1/ulp(||x||^2) ----------------
// Reference does fl32(||x||^2 + ||e||^2 - 2 x.e). ||e||^2 (<3.8e-6) is always
// absorbed by the add to ||x||^2 (~256, half-ulp >= 7.6e-6). Since A is an f32
// on the u-grid of its binade, fl(A - c) = A - u*rint(c/u): the argmin depends
// only on u (A's binade), not A's exact bits. Any accurate f32 ||x||^2 gives
// the right binade.
__global__ __launch_bounds__(256) void tok_invu_kernel(
    const float* __restrict__ x, float* __restrict__ invu) {
  int t = blockIdx.x * 4 + (threadIdx.x >> 6);
  int lane = threadIdx.x & 63;
  const float* row = x + (size_t)t * DIM;
  float s = 0.f;
  #pragma unroll
  for (int i = 0; i < DIM / 64; ++i) {
    float v = row[lane + 64 * i];
    s += v * v;
  }
  #pragma unroll
  for (int off = 32; off; off >>= 1) s += __shfl_down(s, off, 64);
  if (lane == 0) {
    int e;
    frexpf(s, &e);               // s = m * 2^e, m in [0.5,1) -> ulp = 2^(e-24)
    invu[t] = exp2f((float)(24 - e));
  }
}

// ---------------- Kernel B: scores + running arg-best ----------------
// score_k = rint(2*(x.e_k) / u); argmin dist == argmax score, ties -> lowest k.
__global__ __launch_bounds__(256) void vq_main_kernel(
    const float* __restrict__ x, const float* __restrict__ cb,
    const float* __restrict__ invu,
    float* __restrict__ part_r, int* __restrict__ part_i) {
  __shared__ float As[BD][BT + 4];
  __shared__ float Bs[BD][BK + 4];

  const int tt = blockIdx.x & 255;   // token tile 0..255
  const int ks = blockIdx.x >> 8;    // k-split 0..3
  const int tid = threadIdx.x;
  const int ty = tid >> 4;           // 0..15 -> 4 tokens each
  const int tx = tid & 15;           // 0..15 -> 4 codes each
  const int row_s = tid >> 2;        // 0..63 staging row
  const int dq = tid & 3;            // 0..3  staging d-quarter

  float best[4];
  int bidx[4];
  #pragma unroll
  for (int i = 0; i < 4; ++i) { best[i] = -FLT_MAX; bidx[i] = 0x7fffffff; }

  const float4 iuv = *(const float4*)(invu + tt * BT + 4 * ty);
  const float iu[4] = {iuv.x, iuv.y, iuv.z, iuv.w};

  const int kbase0 = ks * KRANGE;

  for (int kc = 0; kc < KRANGE / BK; ++kc) {
    const int kbase = kbase0 + kc * BK;
    float acc[4][4];
    #pragma unroll
    for (int i = 0; i < 4; ++i)
      #pragma unroll
      for (int j = 0; j < 4; ++j) acc[i][j] = 0.f;

    for (int dc = 0; dc < DIM / BD; ++dc) {
      const int dbase = dc * BD;
      const float* xr = x + (size_t)(tt * BT + row_s) * DIM + dbase + dq * 16;
      const float* br = cb + (size_t)(kbase + row_s) * DIM + dbase + dq * 16;
      #pragma unroll
      for (int i = 0; i < 4; ++i) {
        float4 v = *(const float4*)(xr + 4 * i);
        float4 w = *(const float4*)(br + 4 * i);
        int d = dq * 16 + 4 * i;
        As[d + 0][row_s] = v.x; As[d + 1][row_s] = v.y;
        As[d + 2][row_s] = v.z; As[d + 3][row_s] = v.w;
        Bs[d + 0][row_s] = w.x; Bs[d + 1][row_s] = w.y;
        Bs[d + 2][row_s] = w.z; Bs[d + 3][row_s] = w.w;
      }
      __syncthreads();

      #pragma unroll 8
      for (int d = 0; d < BD; ++d) {
        float4 xv = *(const float4*)&As[d][4 * ty];
        float4 ev = *(const float4*)&Bs[d][4 * tx];
        acc[0][0] += xv.x * ev.x; acc[0][1] += xv.x * ev.y;
        acc[0][2] += xv.x * ev.z; acc[0][3] += xv.x * ev.w;
        acc[1][0] += xv.y * ev.x; acc[1][1] += xv.y * ev.y;
        acc[1][2] += xv.y * ev.z; acc[1][3] += xv.y * ev.w;
        acc[2][0] += xv.z * ev.x; acc[2][1] += xv.z * ev.y;
        acc[2][2] += xv.z * ev.z; acc[2][3] += xv.z * ev.w;
        acc[3][0] += xv.w * ev.x; acc[3][1] += xv.w * ev.y;
        acc[3][2] += xv.w * ev.z; acc[3][3] += xv.w * ev.w;
      }
      __syncthreads();
    }

    // quantized score; ascending k scan with strict > keeps lowest idx on ties
    #pragma unroll
    for (int i = 0; i < 4; ++i) {
      #pragma unroll
      for (int j = 0; j < 4; ++j) {
        float r = rintf((2.f * acc[i][j]) * iu[i]);
        if (r > best[i]) { best[i] = r; bidx[i] = kbase + 4 * tx + j; }
      }
    }
  }

  // reduce across the 16 tx lanes (butterfly), lowest-index tie-break
  #pragma unroll
  for (int i = 0; i < 4; ++i) {
    float r = best[i];
    int b = bidx[i];
    #pragma unroll
    for (int m = 1; m < 16; m <<= 1) {
      float orv = __shfl_xor(r, m, 64);
      int ob = __shfl_xor(b, m, 64);
      if (orv > r || (orv == r && ob < b)) { r = orv; b = ob; }
    }
    if (tx == 0) {
      int t = tt * BT + 4 * ty + i;
      part_r[ks * N_TOK + t] = r;
      part_i[ks * N_TOK + t] = b;
    }
  }
}

// ---------------- Kernel C: combine splits, gather, idx, loss partials ----------------
__global__ __launch_bounds__(256) void vq_out_kernel(
    const float* __restrict__ x, const float* __restrict__ cb,
    const float* __restrict__ part_r, const int* __restrict__ part_i,
    float* __restrict__ out, float* __restrict__ lpart) {
  const int tid = threadIdx.x;
  const int tl = tid >> 4;
  const int dq = tid & 15;
  const int token = blockIdx.x * 16 + tl;

  float br = -FLT_MAX;
  int bi = 0x7fffffff;
  #pragma unroll
  for (int s = 0; s < KSPLIT; ++s) {
    float r = part_r[s * N_TOK + token];
    int i = part_i[s * N_TOK + token];
    if (r > br || (r == br && i < bi)) { br = r; bi = i; }
  }
  if (dq == 0) out[OUT_I + token] = (float)bi;

  const float* q = cb + (size_t)bi * DIM;
  const float* xr = x + (size_t)token * DIM;
  float* o = out + (size_t)token * DIM;
  float s = 0.f;
  #pragma unroll
  for (int i = 0; i < 4; ++i) {
    int d = dq * 16 + 4 * i;
    float4 qv = *(const float4*)(q + d);
    float4 xv = *(const float4*)(xr + d);
    *(float4*)(o + d) = qv;
    float a = qv.x - xv.x, b2 = qv.y - xv.y, c = qv.z - xv.z, e = qv.w - xv.w;
    s += a * a + b2 * b2 + c * c + e * e;
  }
  #pragma unroll
  for (int off = 32; off; off >>= 1) s += __shfl_down(s, off, 64);
  __shared__ float red[4];
  int lane = tid & 63, wid = tid >> 6;
  if (lane == 0) red[wid] = s;
  __syncthreads();
  if (tid == 0) lpart[blockIdx.x] = red[0] + red[1] + red[2] + red[3];
}

// ---------------- Kernel D: final loss ----------------
__global__ __launch_bounds__(256) void vq_loss_kernel(
    const float* __restrict__ lpart, float* __restrict__ out) {
  const int tid = threadIdx.x;
  float s = 0.f;
  #pragma unroll
  for (int i = 0; i < 4; ++i) s += lpart[tid + 256 * i];
  #pragma unroll
  for (int off = 32; off; off >>= 1) s += __shfl_down(s, off, 64);
  __shared__ float red[4];
  int lane = tid & 63, wid = tid >> 6;
  if (lane == 0) red[wid] = s;
  __syncthreads();
  if (tid == 0)
    out[OUT_Q + N_TOK] = (red[0] + red[1] + red[2] + red[3]) *
                         (0.25f / (float)(N_TOK * DIM));
}

extern "C" void kernel_launch(void* const* d_in, const int* in_sizes, int n_in,
                              void* d_out, int out_size, void* d_ws, size_t ws_size,
                              hipStream_t stream) {
  const float* x = (const float*)d_in[0];     // (B,T,D) f32
  const float* cb = (const float*)d_in[1];    // (K,D) f32
  float* out = (float*)d_out;

  float* wf = (float*)d_ws;
  float* invu = wf;                             // 16384
  float* part_r = wf + 16384;                   // 65536
  int* part_i = (int*)(wf + 16384 + 65536);     // 65536
  float* lpart = wf + 16384 + 2 * 65536;        // 1024

  tok_invu_kernel<<<N_TOK / 4, 256, 0, stream>>>(x, invu);
  vq_main_kernel<<<(N_TOK / BT) * KSPLIT, 256, 0, stream>>>(x, cb, invu, part_r, part_i);
  vq_out_kernel<<<N_TOK / 16, 256, 0, stream>>>(x, cb, part_r, part_i, out, lpart);
  vq_loss_kernel<<<1, 256, 0, stream>>>(lpart, out);
}

// Round 9
// 561.364 us; speedup vs baseline: 1.8593x; 1.8593x over previous
//
#include <hip/hip_runtime.h>
#include <math.h>
#include <float.h>

// Problem constants (reference: B=8, T=2048, D=256, K=8192)
#define N_TOK 16384
#define DIM   256
#define KCODES 8192
#define OUT_Q (N_TOK * DIM)
#define OUT_I OUT_Q
#define COMMIT_SCALE (0.25f / (float)(N_TOK * DIM))

typedef __attribute__((ext_vector_type(8))) short bf16x8;
typedef __attribute__((ext_vector_type(4))) float f32x4;

// ---------- ws layout (bytes) for the MFMA path ----------
#define WS_XS     0u                        // 16384*512*2 = 16,777,216 (bf16 [xh|xl])
#define WS_ES     16777216u                 // 8192*512*2 = 8,388,608
#define WS_INVU   25165824u                 // 16384*4
#define WS_PR1    25231360u                 // 16384*64*4
#define WS_PI1    29425664u
#define WS_PR2    33619968u
#define WS_IDXF   37814272u                 // 16384*4
#define WS_DCNT   37879808u                 // 64
#define WS_DANGER 37879872u                 // 4096*4
#define WS_P2R    37896256u                 // 4096*16*4
#define WS_P2I    38158400u
#define WS_LPART  38420544u                 // 1024*4
#define WS_NEED   38424640u

__device__ __forceinline__ unsigned short bf16_rne(float f) {
  unsigned b = __float_as_uint(f);
  return (unsigned short)((b + 0x7FFFu + ((b >> 16) & 1u)) >> 16);
}
__device__ __forceinline__ float bf16_to_f(unsigned short h) {
  return __uint_as_float(((unsigned)h) << 16);
}

// ---------------- split_x: x -> [xh|xl] bf16 rows (512 wide) + invu ----------------
// invu = 1/ulp(||x||^2): reference's fl(||x||^2 + ||e||^2 - 2 x.e) quantizes the
// score to this grid (||e||^2 always absorbed); only the binade matters, so any
// accurate f32 sum order works (verified passing in round 4).
__global__ __launch_bounds__(256) void split_x_kernel(
    const float* __restrict__ x, unsigned short* __restrict__ xs,
    float* __restrict__ invu) {
  int row = blockIdx.x * 4 + (threadIdx.x >> 6);
  int lane = threadIdx.x & 63;
  float4 v = *(const float4*)(x + (size_t)row * DIM + lane * 4);
  ushort4 h, l;
  h.x = bf16_rne(v.x); l.x = bf16_rne(v.x - bf16_to_f(h.x));
  h.y = bf16_rne(v.y); l.y = bf16_rne(v.y - bf16_to_f(h.y));
  h.z = bf16_rne(v.z); l.z = bf16_rne(v.z - bf16_to_f(h.z));
  h.w = bf16_rne(v.w); l.w = bf16_rne(v.w - bf16_to_f(h.w));
  unsigned short* orow = xs + (size_t)row * 512;
  *(ushort4*)(orow + lane * 4) = h;
  *(ushort4*)(orow + 256 + lane * 4) = l;
  float s = v.x * v.x + v.y * v.y + v.z * v.z + v.w * v.w;
  #pragma unroll
  for (int off = 32; off; off >>= 1) s += __shfl_xor(s, off, 64);
  if (lane == 0) {
    int e;
    frexpf(s, &e);
    invu[row] = exp2f((float)(24 - e));
  }
}

// ---------------- split_e: cb -> [eh|el] bf16 rows; zero danger counter ----------------
__global__ __launch_bounds__(256) void split_e_kernel(
    const float* __restrict__ cb, unsigned short* __restrict__ es,
    int* __restrict__ dcnt) {
  if (blockIdx.x == 0 && threadIdx.x == 0) *dcnt = 0;
  int row = blockIdx.x * 4 + (threadIdx.x >> 6);
  int lane = threadIdx.x & 63;
  float4 v = *(const float4*)(cb + (size_t)row * DIM + lane * 4);
  ushort4 h, l;
  h.x = bf16_rne(v.x); l.x = bf16_rne(v.x - bf16_to_f(h.x));
  h.y = bf16_rne(v.y); l.y = bf16_rne(v.y - bf16_to_f(h.y));
  h.z = bf16_rne(v.z); l.z = bf16_rne(v.z - bf16_to_f(h.z));
  h.w = bf16_rne(v.w); l.w = bf16_rne(v.w - bf16_to_f(h.w));
  unsigned short* orow = es + (size_t)row * 512;
  *(ushort4*)(orow + lane * 4) = h;
  *(ushort4*)(orow + 256 + lane * 4) = l;
}

// ---------------- main MFMA kernel ----------------
// Grid 8192: ctile = bid&63 (codes, M-side), ttile = bid>>6 (tokens, N-side).
// K' = 768 via (A:[eh|eh|el]) x (B:[xh|xl|xh]); tile 128x128, BK=64 (12 K-steps).
// LDS tiles [128 rows][64 k] bf16 with T2 XOR-swizzle (byte ^= (row&7)<<4) on
// both ds_write (staging) and ds_read (fragments).
// MFMA 16x16x32: C col=lane&15 (token), row=(lane>>4)*4+reg (code)  [m89].
__global__ __launch_bounds__(256) void vq_mfma_kernel(
    const unsigned short* __restrict__ xs, const unsigned short* __restrict__ es,
    const float* __restrict__ invu,
    float* __restrict__ pr1, int* __restrict__ pi1, float* __restrict__ pr2) {
  __shared__ __align__(16) char smem[34816];  // As 16KB | Bs 16KB | merge 1.5KB
  float* mg = (float*)(smem + 32768);

  const int bid = blockIdx.x;
  const int ctile = bid & 63;
  const int ttile = bid >> 6;
  const int tid = threadIdx.x;
  const int w = tid >> 6;
  const int lane = tid & 63;
  const int wm = w >> 1, wn = w & 1;      // wm: code half, wn: token half
  const int l15 = lane & 15, lg = lane >> 4;

  f32x4 acc[4][4];
  #pragma unroll
  for (int mi = 0; mi < 4; ++mi)
    #pragma unroll
    for (int nj = 0; nj < 4; ++nj) acc[mi][nj] = (f32x4){0.f, 0.f, 0.f, 0.f};

  const char* abase = (const char*)es + (size_t)(ctile * 128) * 1024;
  const char* bbase = (const char*)xs + (size_t)(ttile * 128) * 1024;
  const int srow = tid >> 3;            // 0..31
  const int sinner = (tid & 7) * 16;    // 0..112

  for (int kc = 0; kc < 12; ++kc) {
    // byte offsets into the 1024B split rows (A: eh,eh,el chunks; B: xh,xl,xh)
    int ao = (kc < 8) ? (kc & 3) * 128 : 512 + (kc & 3) * 128;
    int bo = (kc < 4) ? kc * 128 : ((kc < 8) ? 512 + (kc - 4) * 128 : (kc - 8) * 128);
    __syncthreads();
    #pragma unroll
    for (int rd = 0; rd < 4; ++rd) {
      int row = rd * 32 + srow;
      int o = row * 128 + sinner;
      int p = o ^ ((row & 7) << 4);
      int4 av = *(const int4*)(abase + (size_t)row * 1024 + ao + sinner);
      int4 bv = *(const int4*)(bbase + (size_t)row * 1024 + bo + sinner);
      *(int4*)(smem + p) = av;
      *(int4*)(smem + 16384 + p) = bv;
    }
    __syncthreads();
    #pragma unroll
    for (int ks = 0; ks < 2; ++ks) {
      bf16x8 b[4];
      #pragma unroll
      for (int nj = 0; nj < 4; ++nj) {
        int row = wn * 64 + nj * 16 + l15;
        int byte = (row * 128 + ks * 64 + lg * 16) ^ ((row & 7) << 4);
        b[nj] = *(const bf16x8*)(smem + 16384 + byte);
      }
      #pragma unroll
      for (int mi = 0; mi < 4; ++mi) {
        int row = wm * 64 + mi * 16 + l15;
        int byte = (row * 128 + ks * 64 + lg * 16) ^ ((row & 7) << 4);
        bf16x8 a = *(const bf16x8*)(smem + byte);
        #pragma unroll
        for (int nj = 0; nj < 4; ++nj)
          acc[mi][nj] = __builtin_amdgcn_mfma_f32_16x16x32_bf16(a, b[nj], acc[mi][nj], 0, 0, 0);
      }
    }
  }

  // Epilogue: per-token quantized-score top-2 over this block's 128 codes.
  const int tok0 = ttile * 128;
  float R1[4], R2[4];
  int I1[4];
  #pragma unroll
  for (int nj = 0; nj < 4; ++nj) {
    int tokl = wn * 64 + nj * 16 + l15;
    float tiu = 2.0f * invu[tok0 + tokl];
    float r1 = -FLT_MAX, r2 = -FLT_MAX;
    int i1 = 0x7fffffff;
    #pragma unroll
    for (int mi = 0; mi < 4; ++mi) {
      #pragma unroll
      for (int r = 0; r < 4; ++r) {
        float sc = rintf(acc[mi][nj][r] * tiu);
        int code = ctile * 128 + wm * 64 + mi * 16 + lg * 4 + r;
        if (sc > r1 || (sc == r1 && code < i1)) { r2 = r1; r1 = sc; i1 = code; }
        else r2 = fmaxf(r2, sc);
      }
    }
    #pragma unroll
    for (int m = 16; m <= 32; m <<= 1) {
      float o1 = __shfl_xor(r1, m, 64);
      int oi = __shfl_xor(i1, m, 64);
      float o2 = __shfl_xor(r2, m, 64);
      if (o1 > r1 || (o1 == r1 && oi < i1)) { r2 = fmaxf(r1, fmaxf(r2, o2)); r1 = o1; i1 = oi; }
      else r2 = fmaxf(r2, fmaxf(o1, o2));
    }
    R1[nj] = r1; R2[nj] = r2; I1[nj] = i1;
  }
  __syncthreads();
  if (wm == 1 && lg == 0) {
    #pragma unroll
    for (int nj = 0; nj < 4; ++nj) {
      int tokl = wn * 64 + nj * 16 + l15;
      mg[tokl * 3 + 0] = R1[nj];
      mg[tokl * 3 + 1] = __int_as_float(I1[nj]);
      mg[tokl * 3 + 2] = R2[nj];
    }
  }
  __syncthreads();
  if (wm == 0 && lg == 0) {
    #pragma unroll
    for (int nj = 0; nj < 4; ++nj) {
      int tokl = wn * 64 + nj * 16 + l15;
      float r1 = R1[nj], r2 = R2[nj];
      int i1 = I1[nj];
      float o1 = mg[tokl * 3 + 0];
      int oi = __float_as_int(mg[tokl * 3 + 1]);
      float o2 = mg[tokl * 3 + 2];
      if (o1 > r1 || (o1 == r1 && oi < i1)) { r2 = fmaxf(r1, fmaxf(r2, o2)); r1 = o1; i1 = oi; }
      else r2 = fmaxf(r2, fmaxf(o1, o2));
      size_t gp = (size_t)(tok0 + tokl) * 64 + ctile;
      pr1[gp] = r1; pi1[gp] = i1; pr2[gp] = r2;
    }
  }
}

// ---------------- combine: global top-2, margin test, danger list ----------------
// margin >= 3 quantized units provably matches numpy's winner (|rint_mine-rint_np|<=1).
__global__ __launch_bounds__(256) void combine_kernel(
    const float* __restrict__ pr1, const int* __restrict__ pi1,
    const float* __restrict__ pr2, int* __restrict__ idxf,
    int* __restrict__ dcnt, int* __restrict__ danger) {
  int t = blockIdx.x * 256 + threadIdx.x;
  const float* r1p = pr1 + (size_t)t * 64;
  const int* i1p = pi1 + (size_t)t * 64;
  const float* r2p = pr2 + (size_t)t * 64;
  float r1 = r1p[0], r2 = r2p[0];
  int i1 = i1p[0];
  for (int j = 1; j < 64; ++j) {
    float o1 = r1p[j], o2 = r2p[j];
    int oi = i1p[j];
    if (o1 > r1 || (o1 == r1 && oi < i1)) { r2 = fmaxf(r1, fmaxf(r2, o2)); r1 = o1; i1 = oi; }
    else r2 = fmaxf(r2, fmaxf(o1, o2));
  }
  idxf[t] = i1;  // provisional (final unless rescued)
  if (r1 - r2 < 3.0f) {
    int slot = atomicAdd(dcnt, 1);
    if (slot < 4096) danger[slot] = t;
  }
}

// ---------------- rescue: exact-f32 rescore of dangerous tokens ----------------
// Gathered clone of the round-4 (passing) kernel: identical rintf arithmetic.
__global__ __launch_bounds__(256) void rescue_kernel(
    const float* __restrict__ x, const float* __restrict__ cb,
    const float* __restrict__ invu, const int* __restrict__ dcnt,
    const int* __restrict__ danger,
    float* __restrict__ p2r, int* __restrict__ p2i) {
  int cnt = *dcnt; if (cnt > 4096) cnt = 4096;
  const int tile = blockIdx.x >> 4;
  const int ks = blockIdx.x & 15;
  if (tile * 64 >= cnt) return;
  __shared__ float As[64][68];
  __shared__ float Bs[64][68];
  __shared__ int tg_sh[64];
  const int tid = threadIdx.x;
  const int ty = tid >> 4, tx = tid & 15;
  const int row_s = tid >> 2, dq = tid & 3;
  if (tid < 64) {
    int s = tile * 64 + tid;
    tg_sh[tid] = danger[s < cnt ? s : cnt - 1];
  }
  __syncthreads();

  float iu[4];
  #pragma unroll
  for (int i = 0; i < 4; ++i) iu[i] = invu[tg_sh[4 * ty + i]];

  float best[4];
  int bidx[4];
  #pragma unroll
  for (int i = 0; i < 4; ++i) { best[i] = -FLT_MAX; bidx[i] = 0x7fffffff; }

  const int kbase0 = ks * 512;
  for (int kc = 0; kc < 8; ++kc) {
    const int kbase = kbase0 + kc * 64;
    float a4[4][4];
    #pragma unroll
    for (int i = 0; i < 4; ++i)
      #pragma unroll
      for (int j = 0; j < 4; ++j) a4[i][j] = 0.f;

    for (int dc = 0; dc < 4; ++dc) {
      const int dbase = dc * 64;
      const float* xr = x + (size_t)tg_sh[row_s] * DIM + dbase + dq * 16;
      const float* br = cb + (size_t)(kbase + row_s) * DIM + dbase + dq * 16;
      #pragma unroll
      for (int i = 0; i < 4; ++i) {
        float4 v = *(const float4*)(xr + 4 * i);
        float4 wv = *(const float4*)(br + 4 * i);
        int d = dq * 16 + 4 * i;
        As[d + 0][row_s] = v.x; As[d + 1][row_s] = v.y;
        As[d + 2][row_s] = v.z; As[d + 3][row_s] = v.w;
        Bs[d + 0][row_s] = wv.x; Bs[d + 1][row_s] = wv.y;
        Bs[d + 2][row_s] = wv.z; Bs[d + 3][row_s] = wv.w;
      }
      __syncthreads();
      #pragma unroll 8
      for (int d = 0; d < 64; ++d) {
        float4 xv = *(const float4*)&As[d][4 * ty];
        float4 ev = *(const float4*)&Bs[d][4 * tx];
        a4[0][0] += xv.x * ev.x; a4[0][1] += xv.x * ev.y;
        a4[0][2] += xv.x * ev.z; a4[0][3] += xv.x * ev.w;
        a4[1][0] += xv.y * ev.x; a4[1][1] += xv.y * ev.y;
        a4[1][2] += xv.y * ev.z; a4[1][3] += xv.y * ev.w;
        a4[2][0] += xv.z * ev.x; a4[2][1] += xv.z * ev.y;
        a4[2][2] += xv.z * ev.z; a4[2][3] += xv.z * ev.w;
        a4[3][0] += xv.w * ev.x; a4[3][1] += xv.w * ev.y;
        a4[3][2] += xv.w * ev.z; a4[3][3] += xv.w * ev.w;
      }
      __syncthreads();
    }
    #pragma unroll
    for (int i = 0; i < 4; ++i) {
      #pragma unroll
      for (int j = 0; j < 4; ++j) {
        float r = rintf((2.f * a4[i][j]) * iu[i]);
        if (r > best[i]) { best[i] = r; bidx[i] = kbase + 4 * tx + j; }
      }
    }
  }
  #pragma unroll
  for (int i = 0; i < 4; ++i) {
    float r = best[i];
    int b = bidx[i];
    #pragma unroll
    for (int m = 1; m < 16; m <<= 1) {
      float orv = __shfl_xor(r, m, 64);
      int ob = __shfl_xor(b, m, 64);
      if (orv > r || (orv == r && ob < b)) { r = orv; b = ob; }
    }
    int slot = tile * 64 + 4 * ty + i;
    if (tx == 0 && slot < cnt) {
      p2r[slot * 16 + ks] = r;
      p2i[slot * 16 + ks] = b;
    }
  }
}

__global__ __launch_bounds__(256) void rescue_final_kernel(
    const int* __restrict__ dcnt, const int* __restrict__ danger,
    const float* __restrict__ p2r, const int* __restrict__ p2i,
    int* __restrict__ idxf) {
  int cnt = *dcnt; if (cnt > 4096) cnt = 4096;
  int slot = blockIdx.x * 256 + threadIdx.x;
  if (slot >= cnt) return;
  float r1 = p2r[slot * 16];
  int i1 = p2i[slot * 16];
  for (int j = 1; j < 16; ++j) {
    float o = p2r[slot * 16 + j];
    int oi = p2i[slot * 16 + j];
    if (o > r1 || (o == r1 && oi < i1)) { r1 = o; i1 = oi; }
  }
  idxf[danger[slot]] = i1;
}

// ---------------- gather + idx + loss partials ----------------
__global__ __launch_bounds__(256) void gather_kernel(
    const float* __restrict__ x, const float* __restrict__ cb,
    const int* __restrict__ idxf, float* __restrict__ out,
    float* __restrict__ lpart) {
  const int tid = threadIdx.x;
  const int tl = tid >> 4;
  const int dq = tid & 15;
  const int token = blockIdx.x * 16 + tl;
  const int bi = idxf[token];
  if (dq == 0) out[OUT_I + token] = (float)bi;
  const float* q = cb + (size_t)bi * DIM;
  const float* xr = x + (size_t)token * DIM;
  float* o = out + (size_t)token * DIM;
  float s = 0.f;
  #pragma unroll
  for (int i = 0; i < 4; ++i) {
    int d = dq * 16 + 4 * i;
    float4 qv = *(const float4*)(q + d);
    float4 xv = *(const float4*)(xr + d);
    *(float4*)(o + d) = qv;
    float a = qv.x - xv.x, b2 = qv.y - xv.y, c = qv.z - xv.z, e = qv.w - xv.w;
    s += a * a + b2 * b2 + c * c + e * e;
  }
  #pragma unroll
  for (int off = 32; off; off >>= 1) s += __shfl_down(s, off, 64);
  __shared__ float red[4];
  int lane = tid & 63, wid = tid >> 6;
  if (lane == 0) red[wid] = s;
  __syncthreads();
  if (tid == 0) lpart[blockIdx.x] = red[0] + red[1] + red[2] + red[3];
}

__global__ __launch_bounds__(256) void vq_loss_kernel(
    const float* __restrict__ lpart, float* __restrict__ out) {
  const int tid = threadIdx.x;
  float s = 0.f;
  #pragma unroll
  for (int i = 0; i < 4; ++i) s += lpart[tid + 256 * i];
  #pragma unroll
  for (int off = 32; off; off >>= 1) s += __shfl_down(s, off, 64);
  __shared__ float red[4];
  int lane = tid & 63, wid = tid >> 6;
  if (lane == 0) red[wid] = s;
  __syncthreads();
  if (tid == 0)
    out[OUT_Q + N_TOK] = (red[0] + red[1] + red[2] + red[3]) * COMMIT_SCALE;
}

// ================= round-4 fallback path (used if ws too small) =================
__global__ __launch_bounds__(256) void tok_invu_kernel(
    const float* __restrict__ x, float* __restrict__ invu) {
  int t = blockIdx.x * 4 + (threadIdx.x >> 6);
  int lane = threadIdx.x & 63;
  const float* row = x + (size_t)t * DIM;
  float s = 0.f;
  #pragma unroll
  for (int i = 0; i < DIM / 64; ++i) {
    float v = row[lane + 64 * i];
    s += v * v;
  }
  #pragma unroll
  for (int off = 32; off; off >>= 1) s += __shfl_down(s, off, 64);
  if (lane == 0) {
    int e;
    frexpf(s, &e);
    invu[t] = exp2f((float)(24 - e));
  }
}

__global__ __launch_bounds__(256) void vq_main_kernel(
    const float* __restrict__ x, const float* __restrict__ cb,
    const float* __restrict__ invu,
    float* __restrict__ part_r, int* __restrict__ part_i) {
  __shared__ float As[64][68];
  __shared__ float Bs[64][68];
  const int tt = blockIdx.x & 255;
  const int ksp = blockIdx.x >> 8;
  const int tid = threadIdx.x;
  const int ty = tid >> 4, tx = tid & 15;
  const int row_s = tid >> 2, dq = tid & 3;
  float best[4];
  int bidx[4];
  #pragma unroll
  for (int i = 0; i < 4; ++i) { best[i] = -FLT_MAX; bidx[i] = 0x7fffffff; }
  const float4 iuv = *(const float4*)(invu + tt * 64 + 4 * ty);
  const float iu[4] = {iuv.x, iuv.y, iuv.z, iuv.w};
  const int kbase0 = ksp * 2048;
  for (int kc = 0; kc < 32; ++kc) {
    const int kbase = kbase0 + kc * 64;
    float a4[4][4];
    #pragma unroll
    for (int i = 0; i < 4; ++i)
      #pragma unroll
      for (int j = 0; j < 4; ++j) a4[i][j] = 0.f;
    for (int dc = 0; dc < 4; ++dc) {
      const int dbase = dc * 64;
      const float* xr = x + (size_t)(tt * 64 + row_s) * DIM + dbase + dq * 16;
      const float* br = cb + (size_t)(kbase + row_s) * DIM + dbase + dq * 16;
      #pragma unroll
      for (int i = 0; i < 4; ++i) {
        float4 v = *(const float4*)(xr + 4 * i);
        float4 wv = *(const float4*)(br + 4 * i);
        int d = dq * 16 + 4 * i;
        As[d + 0][row_s] = v.x; As[d + 1][row_s] = v.y;
        As[d + 2][row_s] = v.z; As[d + 3][row_s] = v.w;
        Bs[d + 0][row_s] = wv.x; Bs[d + 1][row_s] = wv.y;
        Bs[d + 2][row_s] = wv.z; Bs[d + 3][row_s] = wv.w;
      }
      __syncthreads();
      #pragma unroll 8
      for (int d = 0; d < 64; ++d) {
        float4 xv = *(const float4*)&As[d][4 * ty];
        float4 ev = *(const float4*)&Bs[d][4 * tx];
        a4[0][0] += xv.x * ev.x; a4[0][1] += xv.x * ev.y;
        a4[0][2] += xv.x * ev.z; a4[0][3] += xv.x * ev.w;
        a4[1][0] += xv.y * ev.x; a4[1][1] += xv.y * ev.y;
        a4[1][2] += xv.y * ev.z; a4[1][3] += xv.y * ev.w;
        a4[2][0] += xv.z * ev.x; a4[2][1] += xv.z * ev.y;
        a4[2][2] += xv.z * ev.z; a4[2][3] += xv.z * ev.w;
        a4[3][0] += xv.w * ev.x; a4[3][1] += xv.w * ev.y;
        a4[3][2] += xv.w * ev.z; a4[3][3] += xv.w * ev.w;
      }
      __syncthreads();
    }
    #pragma unroll
    for (int i = 0; i < 4; ++i) {
      #pragma unroll
      for (int j = 0; j < 4; ++j) {
        float r = rintf((2.f * a4[i][j]) * iu[i]);
        if (r > best[i]) { best[i] = r; bidx[i] = kbase + 4 * tx + j; }
      }
    }
  }
  #pragma unroll
  for (int i = 0; i < 4; ++i) {
    float r = best[i];
    int b = bidx[i];
    #pragma unroll
    for (int m = 1; m < 16; m <<= 1) {
      float orv = __shfl_xor(r, m, 64);
      int ob = __shfl_xor(b, m, 64);
      if (orv > r || (orv == r && ob < b)) { r = orv; b = ob; }
    }
    if (tx == 0) {
      int t = tt * 64 + 4 * ty + i;
      part_r[ksp * N_TOK + t] = r;
      part_i[ksp * N_TOK + t] = b;
    }
  }
}

__global__ __launch_bounds__(256) void vq_out_kernel(
    const float* __restrict__ x, const float* __restrict__ cb,
    const float* __restrict__ part_r, const int* __restrict__ part_i,
    float* __restrict__ out, float* __restrict__ lpart) {
  const int tid = threadIdx.x;
  const int tl = tid >> 4;
  const int dq = tid & 15;
  const int token = blockIdx.x * 16 + tl;
  float br = -FLT_MAX;
  int bi = 0x7fffffff;
  #pragma unroll
  for (int s = 0; s < 4; ++s) {
    float r = part_r[s * N_TOK + token];
    int i = part_i[s * N_TOK + token];
    if (r > br || (r == br && i < bi)) { br = r; bi = i; }
  }
  if (dq == 0) out[OUT_I + token] = (float)bi;
  const float* q = cb + (size_t)bi * DIM;
  const float* xr = x + (size_t)token * DIM;
  float* o = out + (size_t)token * DIM;
  float s = 0.f;
  #pragma unroll
  for (int i = 0; i < 4; ++i) {
    int d = dq * 16 + 4 * i;
    float4 qv = *(const float4*)(q + d);
    float4 xv = *(const float4*)(xr + d);
    *(float4*)(o + d) = qv;
    float a = qv.x - xv.x, b2 = qv.y - xv.y, c = qv.z - xv.z, e = qv.w - xv.w;
    s += a * a + b2 * b2 + c * c + e * e;
  }
  #pragma unroll
  for (int off = 32; off; off >>= 1) s += __shfl_down(s, off, 64);
  __shared__ float red[4];
  int lane = tid & 63, wid = tid >> 6;
  if (lane == 0) red[wid] = s;
  __syncthreads();
  if (tid == 0) lpart[blockIdx.x] = red[0] + red[1] + red[2] + red[3];
}

// ================= launcher =================
extern "C" void kernel_launch(void* const* d_in, const int* in_sizes, int n_in,
                              void* d_out, int out_size, void* d_ws, size_t ws_size,
                              hipStream_t stream) {
  const float* x = (const float*)d_in[0];
  const float* cb = (const float*)d_in[1];
  float* out = (float*)d_out;

  if (ws_size >= (size_t)WS_NEED) {
    char* w = (char*)d_ws;
    unsigned short* xs = (unsigned short*)(w + WS_XS);
    unsigned short* es = (unsigned short*)(w + WS_ES);
    float* invu = (float*)(w + WS_INVU);
    float* pr1 = (float*)(w + WS_PR1);
    int* pi1 = (int*)(w + WS_PI1);
    float* pr2 = (float*)(w + WS_PR2);
    int* idxf = (int*)(w + WS_IDXF);
    int* dcnt = (int*)(w + WS_DCNT);
    int* danger = (int*)(w + WS_DANGER);
    float* p2r = (float*)(w + WS_P2R);
    int* p2i = (int*)(w + WS_P2I);
    float* lpart = (float*)(w + WS_LPART);

    split_x_kernel<<<N_TOK / 4, 256, 0, stream>>>(x, xs, invu);
    split_e_kernel<<<KCODES / 4, 256, 0, stream>>>(cb, es, dcnt);
    vq_mfma_kernel<<<8192, 256, 0, stream>>>(xs, es, invu, pr1, pi1, pr2);
    combine_kernel<<<N_TOK / 256, 256, 0, stream>>>(pr1, pi1, pr2, idxf, dcnt, danger);
    rescue_kernel<<<1024, 256, 0, stream>>>(x, cb, invu, dcnt, danger, p2r, p2i);
    rescue_final_kernel<<<16, 256, 0, stream>>>(dcnt, danger, p2r, p2i, idxf);
    gather_kernel<<<N_TOK / 16, 256, 0, stream>>>(x, cb, idxf, out, lpart);
    vq_loss_kernel<<<1, 256, 0, stream>>>(lpart, out);
  } else {
    float* wf = (float*)d_ws;
    float* invu = wf;
    float* part_r = wf + 16384;
    int* part_i = (int*)(wf + 16384 + 65536);
    float* lpart = wf + 16384 + 2 * 65536;
    tok_invu_kernel<<<N_TOK / 4, 256, 0, stream>>>(x, invu);
    vq_main_kernel<<<1024, 256, 0, stream>>>(x, cb, invu, part_r, part_i);
    vq_out_kernel<<<N_TOK / 16, 256, 0, stream>>>(x, cb, part_r, part_i, out, lpart);
    vq_loss_kernel<<<1, 256, 0, stream>>>(lpart, out);
  }
}